// Round 1
// baseline (1228.789 us; speedup 1.0000x reference)
//
#include <hip/hip_runtime.h>
#include <stdint.h>

#define M_DIM 8192
#define N_DIM 11008
#define K_DIM 4096

#define BM 128
#define BN 128
#define BK 64

typedef unsigned short u16;
typedef short short8 __attribute__((ext_vector_type(8)));
typedef float f32x4 __attribute__((ext_vector_type(4)));
typedef u16 u16x8 __attribute__((ext_vector_type(8)));

// ---------- helpers ----------

__device__ __forceinline__ u16 f2bf_rne(float f) {
    uint32_t u = __float_as_uint(f);
    u += 0x7FFFu + ((u >> 16) & 1u);   // round-to-nearest-even
    return (u16)(u >> 16);
}

__device__ __forceinline__ u16 signbf(float f) {
    if (f == 0.0f) return 0;
    return (u16)(0x3F80u | ((__float_as_uint(f) >> 16) & 0x8000u)); // ±1.0 bf16
}

// ---------- pre-pass: f32 x -> bf16 ----------

__global__ void convert_x_kernel(const float* __restrict__ x, u16* __restrict__ xb, long long n) {
    long long i = ((long long)blockIdx.x * blockDim.x + threadIdx.x) * 8;
    long long stride = (long long)gridDim.x * blockDim.x * 8;
    for (; i < n; i += stride) {
        float4 f0 = *(const float4*)(x + i);
        float4 f1 = *(const float4*)(x + i + 4);
        u16x8 r;
        r[0] = f2bf_rne(f0.x); r[1] = f2bf_rne(f0.y);
        r[2] = f2bf_rne(f0.z); r[3] = f2bf_rne(f0.w);
        r[4] = f2bf_rne(f1.x); r[5] = f2bf_rne(f1.y);
        r[6] = f2bf_rne(f1.z); r[7] = f2bf_rne(f1.w);
        *(u16x8*)(xb + i) = r;
    }
}

// ---------- pre-pass: f32 w -> sign(w) in bf16 (exact {-1,0,+1}) ----------

__global__ void convert_w_kernel(const float* __restrict__ w, u16* __restrict__ wb, long long n) {
    long long i = ((long long)blockIdx.x * blockDim.x + threadIdx.x) * 8;
    long long stride = (long long)gridDim.x * blockDim.x * 8;
    for (; i < n; i += stride) {
        float4 f0 = *(const float4*)(w + i);
        float4 f1 = *(const float4*)(w + i + 4);
        u16x8 r;
        r[0] = signbf(f0.x); r[1] = signbf(f0.y);
        r[2] = signbf(f0.z); r[3] = signbf(f0.w);
        r[4] = signbf(f1.x); r[5] = signbf(f1.y);
        r[6] = signbf(f1.z); r[7] = signbf(f1.w);
        *(u16x8*)(wb + i) = r;
    }
}

// ---------- main GEMM: C[M,N] = A[M,K] * B[N,K]^T + bias ----------
// m97 structure: 128x128 tile, BK=64, 4 waves (2x2), 16x16x32 bf16 MFMA,
// single-buffered LDS via global_load_lds width=16, 2 barriers per K-step.

__global__ __launch_bounds__(256) void ternary_gemm_kernel(
    const u16* __restrict__ A, const u16* __restrict__ B,
    const float* __restrict__ bias, float* __restrict__ out)
{
    __shared__ u16 As[BM * BK];   // 16 KiB
    __shared__ u16 Bs[BN * BK];   // 16 KiB

    const int tid  = threadIdx.x;
    const int lane = tid & 63;
    const int wid  = tid >> 6;        // 0..3
    const int wr   = wid >> 1;        // wave row (0..1) -> 64-row slab
    const int wc   = wid & 1;         // wave col (0..1) -> 64-col slab
    const int l15  = lane & 15;
    const int l4   = lane >> 4;       // 0..3

    const int bid  = blockIdx.x;
    const int bn   = bid % (N_DIM / BN);
    const int bm   = bid / (N_DIM / BN);
    const int brow = bm * BM;
    const int bcol = bn * BN;

    f32x4 acc[4][4] = {};

    for (int kt = 0; kt < K_DIM; kt += BK) {
        // ---- stage A,B tiles: 4 passes x 256 threads x 16B each per matrix ----
        #pragma unroll
        for (int p = 0; p < 4; ++p) {
            int idx  = p * 256 + tid;          // 0..1023 16B-slots
            int row  = idx >> 3;               // tile row (8 slots of 8 bf16 = 64 = BK)
            int koff = (idx & 7) * 8;
            const u16* ga = A + (size_t)(brow + row) * K_DIM + kt + koff;
            const u16* gb = B + (size_t)(bcol + row) * K_DIM + kt + koff;
            // wave-uniform LDS dest: lane l lands at base + l*16 (linear layout)
            char* la = (char*)As + (size_t)(p * 256 + wid * 64) * 16;
            char* lb = (char*)Bs + (size_t)(p * 256 + wid * 64) * 16;
            __builtin_amdgcn_global_load_lds(
                (const __attribute__((address_space(1))) uint32_t*)ga,
                (__attribute__((address_space(3))) uint32_t*)la, 16, 0, 0);
            __builtin_amdgcn_global_load_lds(
                (const __attribute__((address_space(1))) uint32_t*)gb,
                (__attribute__((address_space(3))) uint32_t*)lb, 16, 0, 0);
        }
        __syncthreads();   // drains vmcnt before barrier (compiler-emitted)

        // ---- compute: 2 K-slices of 32, 4x4 fragments per wave ----
        #pragma unroll
        for (int kk = 0; kk < 2; ++kk) {
            short8 a[4], b[4];
            #pragma unroll
            for (int m = 0; m < 4; ++m)
                a[m] = *(const short8*)&As[(wr * 64 + m * 16 + l15) * BK + kk * 32 + l4 * 8];
            #pragma unroll
            for (int n = 0; n < 4; ++n)
                b[n] = *(const short8*)&Bs[(wc * 64 + n * 16 + l15) * BK + kk * 32 + l4 * 8];
            #pragma unroll
            for (int m = 0; m < 4; ++m)
                #pragma unroll
                for (int n = 0; n < 4; ++n)
                    acc[m][n] = __builtin_amdgcn_mfma_f32_16x16x32_bf16(
                        a[m], b[n], acc[m][n], 0, 0, 0);
        }
        __syncthreads();
    }

    // ---- epilogue: C/D layout col=lane&15, row=(lane>>4)*4+reg ----
    #pragma unroll
    for (int n = 0; n < 4; ++n) {
        int col = bcol + wc * 64 + n * 16 + l15;
        float bv = bias[col];
        #pragma unroll
        for (int m = 0; m < 4; ++m) {
            int row0 = brow + wr * 64 + m * 16 + l4 * 4;
            #pragma unroll
            for (int r = 0; r < 4; ++r)
                out[(size_t)(row0 + r) * N_DIM + col] = acc[m][n][r] + bv;
        }
    }
}

// ---------- fallback (only if workspace too small): correct but slow ----------

__global__ void naive_kernel(const float* __restrict__ x, const float* __restrict__ w,
                             const float* __restrict__ bias, float* __restrict__ out) {
    long long o = (long long)blockIdx.x * blockDim.x + threadIdx.x;
    if (o >= (long long)M_DIM * N_DIM) return;
    int row = (int)(o / N_DIM), col = (int)(o % N_DIM);
    float s = 0.0f;
    const float* xr = x + (size_t)row * K_DIM;
    const float* wr = w + (size_t)col * K_DIM;
    for (int k = 0; k < K_DIM; ++k) {
        float wv = wr[k];
        s += (wv > 0.0f) ? xr[k] : ((wv < 0.0f) ? -xr[k] : 0.0f);
    }
    out[o] = s + bias[col];
}

// ---------- launch ----------

extern "C" void kernel_launch(void* const* d_in, const int* in_sizes, int n_in,
                              void* d_out, int out_size, void* d_ws, size_t ws_size,
                              hipStream_t stream) {
    const float* x    = (const float*)d_in[0];
    const float* w    = (const float*)d_in[1];
    const float* bias = (const float*)d_in[2];
    float* out        = (float*)d_out;

    const size_t xb_bytes = (size_t)M_DIM * K_DIM * sizeof(u16);  // 64 MiB
    const size_t wb_bytes = (size_t)N_DIM * K_DIM * sizeof(u16);  // 86 MiB

    if (ws_size >= xb_bytes + wb_bytes) {
        u16* xb = (u16*)d_ws;
        u16* wb = (u16*)((char*)d_ws + xb_bytes);

        const long long nx = (long long)M_DIM * K_DIM;   // 33.5M, /8 exact
        const long long nw = (long long)N_DIM * K_DIM;   // 45.1M, /8 exact
        convert_x_kernel<<<(int)(nx / (256 * 8)), 256, 0, stream>>>(x, xb, nx);
        convert_w_kernel<<<(int)(nw / (256 * 8)), 256, 0, stream>>>(w, wb, nw);

        const int grid = (M_DIM / BM) * (N_DIM / BN);    // 64 * 86 = 5504
        ternary_gemm_kernel<<<grid, 256, 0, stream>>>(xb, wb, bias, out);
    } else {
        const long long total = (long long)M_DIM * N_DIM;
        naive_kernel<<<(int)((total + 255) / 256), 256, 0, stream>>>(x, w, bias, out);
    }
}

// Round 2
// 715.488 us; speedup vs baseline: 1.7174x; 1.7174x over previous
//
#include <hip/hip_runtime.h>
#include <stdint.h>

#define M_DIM 8192
#define N_DIM 11008
#define K_DIM 4096

#define BM 256
#define BN 256
#define BK 64
#define NT (K_DIM / BK)          // 64 K-tiles
#define GRID_M (M_DIM / BM)      // 32
#define GRID_N (N_DIM / BN)      // 43
#define NWG (GRID_M * GRID_N)    // 1376 (divisible by 8 -> simple XCD swizzle OK)

#define BUF_ELEMS (BM * BK)      // 16384 u16 = 32 KiB per buffer

typedef unsigned short u16;
typedef short short8 __attribute__((ext_vector_type(8)));
typedef float f32x4 __attribute__((ext_vector_type(4)));
typedef u16 u16x8 __attribute__((ext_vector_type(8)));

// ---------- helpers ----------

__device__ __forceinline__ u16 f2bf_rne(float f) {
    uint32_t u = __float_as_uint(f);
    u += 0x7FFFu + ((u >> 16) & 1u);   // round-to-nearest-even
    return (u16)(u >> 16);
}

__device__ __forceinline__ u16 signbf(float f) {
    if (f == 0.0f) return 0;
    return (u16)(0x3F80u | ((__float_as_uint(f) >> 16) & 0x8000u)); // ±1.0 bf16
}

__device__ __forceinline__ f32x4 MFMA(short8 a, short8 b, f32x4 c) {
    return __builtin_amdgcn_mfma_f32_16x16x32_bf16(a, b, c, 0, 0, 0);
}

#define GLOAD16(src, dst)                                                              \
    __builtin_amdgcn_global_load_lds(                                                  \
        (const __attribute__((address_space(1))) uint32_t*)(src),                      \
        (__attribute__((address_space(3))) uint32_t*)(dst), 16, 0, 0)

// ---------- pre-pass: f32 x -> bf16 ----------

__global__ void convert_x_kernel(const float* __restrict__ x, u16* __restrict__ xb, long long n) {
    long long i = ((long long)blockIdx.x * blockDim.x + threadIdx.x) * 8;
    long long stride = (long long)gridDim.x * blockDim.x * 8;
    for (; i < n; i += stride) {
        float4 f0 = *(const float4*)(x + i);
        float4 f1 = *(const float4*)(x + i + 4);
        u16x8 r;
        r[0] = f2bf_rne(f0.x); r[1] = f2bf_rne(f0.y);
        r[2] = f2bf_rne(f0.z); r[3] = f2bf_rne(f0.w);
        r[4] = f2bf_rne(f1.x); r[5] = f2bf_rne(f1.y);
        r[6] = f2bf_rne(f1.z); r[7] = f2bf_rne(f1.w);
        *(u16x8*)(xb + i) = r;
    }
}

// ---------- pre-pass: f32 w -> sign(w) in bf16 (exact {-1,0,+1}) ----------

__global__ void convert_w_kernel(const float* __restrict__ w, u16* __restrict__ wb, long long n) {
    long long i = ((long long)blockIdx.x * blockDim.x + threadIdx.x) * 8;
    long long stride = (long long)gridDim.x * blockDim.x * 8;
    for (; i < n; i += stride) {
        float4 f0 = *(const float4*)(w + i);
        float4 f1 = *(const float4*)(w + i + 4);
        u16x8 r;
        r[0] = signbf(f0.x); r[1] = signbf(f0.y);
        r[2] = signbf(f0.z); r[3] = signbf(f0.w);
        r[4] = signbf(f1.x); r[5] = signbf(f1.y);
        r[6] = signbf(f1.z); r[7] = signbf(f1.w);
        *(u16x8*)(wb + i) = r;
    }
}

// ---------- main GEMM: 256x256 tile, BK=64, 8 waves, 8-phase (4 phases/K-tile,
// 2 K-tiles per LDS residency), counted vmcnt, XOR-swizzled LDS (T1+T2+T3/T4+T5) ----------
//
// Wave striping (interleaved): wave (wm,wn) owns
//   A rows:  m*32 + wm*16 + [0,16)   for m = 0..7
//   B rows:  n*64 + wn*16 + [0,16)   for n = 0..3
// so each phase's quadrant maps to exact half-tiles:
//   P0: A-lo,B-lo   P1: A-lo,B-hi   P2: A-hi,B-lo   P3: A-hi,B-hi
//
// Staging schedule (issue points; each half = 2 global_load_lds/thread):
//   P0(t): A-hi(t+1)   P1(t): B-hi(t+1)   P2(t): A-lo(t+2)   P3(t): B-lo(t+2)
// Every issue is >=1 barrier after the last ds_read of the slot it overwrites.
// vmcnt(4) at tile end leaves the newest 2 halves in flight; guarantees tile
// t+1 fully landed. Last two tiles drain with vmcnt(0).
//
// LDS swizzle (both-sides involution, rule #21): slot ^= (row & 7). Writes are
// linear (gload_lds) with the XOR applied to the per-lane GLOBAL source; reads
// apply the same XOR -> 2 lanes/bank (free, m136).

__global__ __launch_bounds__(512) void ternary_gemm_256(
    const u16* __restrict__ A, const u16* __restrict__ B,
    const float* __restrict__ bias, float* __restrict__ out)
{
    extern __shared__ u16 lds[];
    u16* As = lds;                    // [2][BUF_ELEMS]
    u16* Bs = lds + 2 * BUF_ELEMS;    // [2][BUF_ELEMS]

    const int tid  = threadIdx.x;
    const int lane = tid & 63;
    const int wid  = tid >> 6;        // 0..7
    const int wm   = wid >> 2;        // 0..1
    const int wn   = wid & 3;         // 0..3
    const int l15  = lane & 15;
    const int l4   = lane >> 4;       // 0..3
    const int p7   = lane & 7;

    // T1: bijective XCD swizzle (NWG % 8 == 0), then bn-minor for A-panel L2 reuse
    const int bid = blockIdx.x;
    const int swz = (bid & 7) * (NWG / 8) + (bid >> 3);
    const int bm  = swz / GRID_N;
    const int bn  = swz % GRID_N;
    const long brow = (long)bm * BM;
    const long bcol = (long)bn * BN;

    // ---- staging addressing (per-thread constant) ----
    // instruction r covers rows r*64 + (tid>>3), LDS slot tid&7;
    // global source slot = (tid&7) ^ (row&7)  (row&7 == (tid>>3)&7 since r*64 % 8 == 0)
    const int rowt = tid >> 3;                       // 0..63
    const int sx   = (tid & 7) ^ (rowt & 7);
    const u16* pA = A + (size_t)(brow + rowt) * K_DIM + sx * 8;
    const u16* pB = B + (size_t)(bcol + rowt) * K_DIM + sx * 8;

    // stage one half-tile (h=0 lo rows 0-127, h=1 hi rows 128-255) of tile t
    auto stage = [&](const u16* base, u16* ldsmat, int t, int h) {
        const int b = t & 1;
        #pragma unroll
        for (int rr = 0; rr < 2; ++rr) {
            const int r = h * 2 + rr;
            GLOAD16(base + (size_t)r * (64 * K_DIM) + (size_t)t * BK,
                    ldsmat + b * BUF_ELEMS + r * 4096 + wid * 512);
        }
    };

    // ---- fragment read addressing ----
    const int slot0 = l4 ^ p7;          // kk=0 swizzled 16B-slot
    const int slot1 = slot0 ^ 4;        // kk=1
    const int aBase = (wm * 16 + l15) * 64;
    const int bBase = (wn * 16 + l15) * 64;

    auto rdA = [&](int b, int mg, int kk) -> short8 {
        return *(const short8*)&As[b * BUF_ELEMS + aBase + mg * 2048 + (kk ? slot1 : slot0) * 8];
    };
    auto rdB = [&](int b, int ng, int kk) -> short8 {
        return *(const short8*)&Bs[b * BUF_ELEMS + bBase + ng * 4096 + (kk ? slot1 : slot0) * 8];
    };

    f32x4 acc[8][4];
    #pragma unroll
    for (int m = 0; m < 8; ++m)
        #pragma unroll
        for (int n = 0; n < 4; ++n) acc[m][n] = (f32x4){0.f, 0.f, 0.f, 0.f};

    // ---- prologue: tile 0 (4 halves) + A-lo(1), B-lo(1); wait oldest 8 ----
    stage(pA, As, 0, 0); stage(pB, Bs, 0, 0);
    stage(pA, As, 0, 1); stage(pB, Bs, 0, 1);
    stage(pA, As, 1, 0); stage(pB, Bs, 1, 0);
    asm volatile("s_waitcnt vmcnt(4)" ::: "memory");
    __builtin_amdgcn_s_barrier();

    short8 af[4][2], bl[2][2], bh[2][2];

    for (int t = 0; t < NT; ++t) {
        const int b = t & 1;

        // ---- P0: read A-lo + B-lo frags; stage A-hi(t+1); MFMA (m0-3, n0-1) ----
        #pragma unroll
        for (int m = 0; m < 4; ++m) { af[m][0] = rdA(b, m, 0); af[m][1] = rdA(b, m, 1); }
        #pragma unroll
        for (int n = 0; n < 2; ++n) { bl[n][0] = rdB(b, n, 0); bl[n][1] = rdB(b, n, 1); }
        if (t + 1 < NT) stage(pA, As, t + 1, 1);
        __builtin_amdgcn_s_barrier();
        __builtin_amdgcn_s_setprio(1);
        #pragma unroll
        for (int m = 0; m < 4; ++m)
            #pragma unroll
            for (int n = 0; n < 2; ++n) {
                acc[m][n] = MFMA(af[m][0], bl[n][0], acc[m][n]);
                acc[m][n] = MFMA(af[m][1], bl[n][1], acc[m][n]);
            }
        __builtin_amdgcn_s_setprio(0);
        __builtin_amdgcn_sched_barrier(0);
        __builtin_amdgcn_s_barrier();

        // ---- P1: read B-hi frags; stage B-hi(t+1); MFMA (m0-3, n2-3) ----
        #pragma unroll
        for (int n = 0; n < 2; ++n) { bh[n][0] = rdB(b, n + 2, 0); bh[n][1] = rdB(b, n + 2, 1); }
        if (t + 1 < NT) stage(pB, Bs, t + 1, 1);
        __builtin_amdgcn_s_barrier();
        __builtin_amdgcn_s_setprio(1);
        #pragma unroll
        for (int m = 0; m < 4; ++m)
            #pragma unroll
            for (int n = 0; n < 2; ++n) {
                acc[m][n + 2] = MFMA(af[m][0], bh[n][0], acc[m][n + 2]);
                acc[m][n + 2] = MFMA(af[m][1], bh[n][1], acc[m][n + 2]);
            }
        __builtin_amdgcn_s_setprio(0);
        __builtin_amdgcn_sched_barrier(0);
        __builtin_amdgcn_s_barrier();

        // ---- P2: read A-hi frags (overwrite af regs); stage A-lo(t+2); MFMA (m4-7, n0-1) ----
        #pragma unroll
        for (int m = 0; m < 4; ++m) { af[m][0] = rdA(b, m + 4, 0); af[m][1] = rdA(b, m + 4, 1); }
        if (t + 2 < NT) stage(pA, As, t + 2, 0);
        __builtin_amdgcn_s_barrier();
        __builtin_amdgcn_s_setprio(1);
        #pragma unroll
        for (int m = 0; m < 4; ++m)
            #pragma unroll
            for (int n = 0; n < 2; ++n) {
                acc[m + 4][n] = MFMA(af[m][0], bl[n][0], acc[m + 4][n]);
                acc[m + 4][n] = MFMA(af[m][1], bl[n][1], acc[m + 4][n]);
            }
        __builtin_amdgcn_s_setprio(0);
        __builtin_amdgcn_sched_barrier(0);
        __builtin_amdgcn_s_barrier();

        // ---- P3: stage B-lo(t+2); MFMA (m4-7, n2-3); tile-end vmcnt ----
        if (t + 2 < NT) stage(pB, Bs, t + 2, 0);
        __builtin_amdgcn_s_barrier();
        __builtin_amdgcn_s_setprio(1);
        #pragma unroll
        for (int m = 0; m < 4; ++m)
            #pragma unroll
            for (int n = 0; n < 2; ++n) {
                acc[m + 4][n + 2] = MFMA(af[m][0], bh[n][0], acc[m + 4][n + 2]);
                acc[m + 4][n + 2] = MFMA(af[m][1], bh[n][1], acc[m + 4][n + 2]);
            }
        __builtin_amdgcn_s_setprio(0);
        __builtin_amdgcn_sched_barrier(0);
        if (t < NT - 2) { asm volatile("s_waitcnt vmcnt(4)" ::: "memory"); }
        else            { asm volatile("s_waitcnt vmcnt(0)" ::: "memory"); }
        __builtin_amdgcn_s_barrier();
    }

    // ---- epilogue: C/D layout col=lane&15, row=(lane>>4)*4+reg (m89-verified) ----
    #pragma unroll
    for (int n = 0; n < 4; ++n) {
        const int col = (int)bcol + n * 64 + wn * 16 + l15;
        const float bv = bias[col];
        #pragma unroll
        for (int m = 0; m < 8; ++m) {
            const size_t row0 = (size_t)brow + m * 32 + wm * 16 + l4 * 4;
            #pragma unroll
            for (int r = 0; r < 4; ++r)
                out[(row0 + r) * N_DIM + col] = acc[m][n][r] + bv;
        }
    }
}

// ---------- fallback (only if workspace too small): correct but slow ----------

__global__ void naive_kernel(const float* __restrict__ x, const float* __restrict__ w,
                             const float* __restrict__ bias, float* __restrict__ out) {
    long long o = (long long)blockIdx.x * blockDim.x + threadIdx.x;
    if (o >= (long long)M_DIM * N_DIM) return;
    int row = (int)(o / N_DIM), col = (int)(o % N_DIM);
    float s = 0.0f;
    const float* xr = x + (size_t)row * K_DIM;
    const float* wr = w + (size_t)col * K_DIM;
    for (int k = 0; k < K_DIM; ++k) {
        float wv = wr[k];
        s += (wv > 0.0f) ? xr[k] : ((wv < 0.0f) ? -xr[k] : 0.0f);
    }
    out[o] = s + bias[col];
}

// ---------- launch ----------

extern "C" void kernel_launch(void* const* d_in, const int* in_sizes, int n_in,
                              void* d_out, int out_size, void* d_ws, size_t ws_size,
                              hipStream_t stream) {
    const float* x    = (const float*)d_in[0];
    const float* w    = (const float*)d_in[1];
    const float* bias = (const float*)d_in[2];
    float* out        = (float*)d_out;

    const size_t xb_bytes = (size_t)M_DIM * K_DIM * sizeof(u16);  // 64 MiB
    const size_t wb_bytes = (size_t)N_DIM * K_DIM * sizeof(u16);  // 86 MiB

    if (ws_size >= xb_bytes + wb_bytes) {
        u16* xb = (u16*)d_ws;
        u16* wb = (u16*)((char*)d_ws + xb_bytes);

        const long long nx = (long long)M_DIM * K_DIM;
        const long long nw = (long long)N_DIM * K_DIM;
        convert_x_kernel<<<(int)(nx / (256 * 8)), 256, 0, stream>>>(x, xb, nx);
        convert_w_kernel<<<(int)(nw / (256 * 8)), 256, 0, stream>>>(w, wb, nw);

        hipFuncSetAttribute(reinterpret_cast<const void*>(ternary_gemm_256),
                            hipFuncAttributeMaxDynamicSharedMemorySize, 131072);
        ternary_gemm_256<<<NWG, 512, 131072, stream>>>(xb, wb, bias, out);
    } else {
        const long long total = (long long)M_DIM * N_DIM;
        naive_kernel<<<(int)((total + 255) / 256), 256, 0, stream>>>(x, w, bias, out);
    }
}